// Round 13
// baseline (53.303 us; speedup 1.0000x reference)
//
#include <hip/hip_runtime.h>
#include <math.h>

#define BB 256
#define NN 50
#define DD 128
#define MAXA 2000
#define NEGV -9e15f
#define NATTR 32                       // 16 m-groups x 2 col-halves, full K each

// u16 strides; 16B-granule strides are ODD (17/9/5) -> bank-quads balanced, NO XOR
#define H_S   136                      // H  [64 i][128 d + pad]
#define HT_S  72                       // HT [128 d][64 i + pad]
#define AL_S  72                       // alpha [64 i][64 j + pad]

#define H_OFF   0
#define HT_OFF  (64 * H_S)             // 8704
#define AL_OFF  (HT_OFF + 128 * HT_S)  // 17920
#define ADJ_OFF (AL_OFF + 64 * AL_S)   // 22528
#define LDS_US  (ADJ_OFF + 64 * 64)    // 26624 u16 = 53248 B

typedef __attribute__((ext_vector_type(8))) short        s8b;
typedef __attribute__((ext_vector_type(4))) float        f32x4;
typedef __attribute__((ext_vector_type(4))) unsigned int u32x4;

// HW packed f32x2 -> bf16x2 (RNE), 1 VALU op (no builtin on gfx950 -> asm)
static __device__ __forceinline__ unsigned int pack2(float lo, float hi) {
    unsigned int r;
    asm("v_cvt_pk_bf16_f32 %0, %1, %2" : "=v"(r) : "v"(lo), "v"(hi));
    return r;
}
static __device__ __forceinline__ float bf2f(unsigned int s) {
    return __uint_as_float(s << 16);
}
static __device__ __forceinline__ f32x4 mfma16(u32x4 a, u32x4 b, f32x4 c) {
    return __builtin_amdgcn_mfma_f32_16x16x32_bf16(
        __builtin_bit_cast(s8b, a), __builtin_bit_cast(s8b, b), c, 0, 0, 0);
}

__global__ __launch_bounds__(256) void sg_fused_kernel(
    const int* __restrict__ inputs,      // [B,N]
    const int* __restrict__ adj,         // [B,N,N]
    const float* __restrict__ A_attr,    // [B,MAXA]
    const float* __restrict__ embedding, // [N_NODE,D]
    const float* __restrict__ attr_emb,  // [MAXA,D]
    const float* __restrict__ a0,
    const float* __restrict__ a1,
    const float* __restrict__ a2,
    const float* __restrict__ a3,
    float* __restrict__ out,             // [B,N,D]
    float* __restrict__ attr_out)        // [B,D]
{
    __shared__ __align__(16) unsigned short sh[LDS_US];
    const int blk  = blockIdx.x;
    const int tid  = threadIdx.x;
    const int w    = tid >> 6;
    const int lane = tid & 63;
    const int g    = lane >> 4;
    const int c    = lane & 15;
    const int goff = g * 8;

    if (blk < NATTR) {
        // ===== attr GEMM: full K per wave, register double-buffer, direct store =====
        // block: m-group mg (16 rows) x col-half ch (64 cols); wave w: 16-col tile
        const int mg   = blk >> 1;
        const int ch   = blk & 1;
        const int m0   = mg * 16;
        const int colb = ch * 64 + w * 16;
        const float* Arow = A_attr + (size_t)(m0 + c) * MAXA;
        const float* Ecol = attr_emb + colb + c;

        f32x4 acc = (f32x4){0.f, 0.f, 0.f, 0.f};

        float4 aLA, aHA, aLB, aHB;
        float  evA[8], evB[8];

        auto loadc = [&](int k0, bool tail, float4& aL, float4& aH, float (&ev)[8]) {
            // tail (chunk 62): lanes g>=2 have k>=2000 entirely -> zeros;
            // g<2 lanes are fully in-bounds (k <= 1999).
            if (!tail || g < 2) {
                aL = *(const float4*)(Arow + k0 + goff);
                aH = *(const float4*)(Arow + k0 + goff + 4);
                #pragma unroll
                for (int p = 0; p < 8; ++p)
                    ev[p] = Ecol[(size_t)(k0 + goff + p) * DD];
            } else {
                aL = make_float4(0.f, 0.f, 0.f, 0.f);
                aH = make_float4(0.f, 0.f, 0.f, 0.f);
                #pragma unroll
                for (int p = 0; p < 8; ++p) ev[p] = 0.f;
            }
        };
        auto compute = [&](const float4& aL, const float4& aH, const float (&ev)[8]) {
            u32x4 af, bf_;
            af[0] = pack2(aL.x, aL.y); af[1] = pack2(aL.z, aL.w);
            af[2] = pack2(aH.x, aH.y); af[3] = pack2(aH.z, aH.w);
            bf_[0] = pack2(ev[0], ev[1]); bf_[1] = pack2(ev[2], ev[3]);
            bf_[2] = pack2(ev[4], ev[5]); bf_[3] = pack2(ev[6], ev[7]);
            acc = mfma16(af, bf_, acc);
        };

        loadc(0, false, aLA, aHA, evA);
        #pragma unroll
        for (int t = 0; t < 31; ++t) {
            loadc((2 * t + 1) * 32, false, aLB, aHB, evB);
            compute(aLA, aHA, evA);
            loadc((2 * t + 2) * 32, (2 * t + 2) == 62, aLA, aHA, evA);
            compute(aLB, aHB, evB);
        }
        compute(aLA, aHA, evA);          // chunk 62

        #pragma unroll
        for (int reg = 0; reg < 4; ++reg)
            attr_out[(size_t)(m0 + g * 4 + reg) * DD + colb + c] = acc[reg];
        return;
    }

    // ================= GAT: one block per batch, wave w = i-tile w =================
    const int b = blk - NATTR;

    // ---- issue embedding gathers EARLY (latency hides under adj staging) ----
    const int  i_   = lane;
    const bool live = (i_ < NN);
    int node = 0;
    if (live) node = inputs[b * NN + i_];
    float4 gv[8];
    #pragma unroll
    for (int n = 0; n < 8; ++n) {
        gv[n] = make_float4(0.f, 0.f, 0.f, 0.f);
        if (live) gv[n] = *(const float4*)(embedding + (size_t)node * DD + (w * 8 + n) * 4);
    }
    // ---- adj -> LDS (zero-padded to 64x64) ----
    for (int idx = tid; idx < 4096; idx += 256) {
        const int i = idx >> 6, j = idx & 63;
        int a = 0;
        if (i < NN && j < NN) a = adj[(size_t)b * (NN * NN) + i * NN + j];
        sh[ADJ_OFF + idx] = (unsigned short)a;
    }
    // ---- convert (cvt_pk) + store H (row-major) and HT (transposed) ----
    #pragma unroll
    for (int n = 0; n < 8; ++n) {
        const int d4 = w * 8 + n;
        const unsigned int pk01 = pack2(gv[n].x, gv[n].y);
        const unsigned int pk23 = pack2(gv[n].z, gv[n].w);
        *(uint2*)(sh + H_OFF + i_ * H_S + d4 * 4) = make_uint2(pk01, pk23);
        sh[HT_OFF + (d4 * 4 + 0) * HT_S + i_] = (unsigned short)pk01;
        sh[HT_OFF + (d4 * 4 + 1) * HT_S + i_] = (unsigned short)(pk01 >> 16);
        sh[HT_OFF + (d4 * 4 + 2) * HT_S + i_] = (unsigned short)pk23;
        sh[HT_OFF + (d4 * 4 + 3) * HT_S + i_] = (unsigned short)(pk23 >> 16);
    }
    __syncthreads();

    // ---- this wave's A-side row fragments ----
    u32x4 hA[4];
    #pragma unroll
    for (int dt = 0; dt < 4; ++dt)
        hA[dt] = *(const u32x4*)(const void*)(sh + H_OFF + (w * 16 + c) * H_S + dt * 32 + goff);

    // ---- scores, dt-outer: e_k = (H⊙0.6a_k)·H^T + (|H|⊙0.4a_k)·|H|^T ----
    f32x4 accS[4][4];                 // [jt][k]
    #pragma unroll
    for (int jt = 0; jt < 4; ++jt)
        #pragma unroll
        for (int k = 0; k < 4; ++k) accS[jt][k] = (f32x4){0.f, 0.f, 0.f, 0.f};

    #pragma unroll
    for (int dt = 0; dt < 4; ++dt) {
        float hf8[8], hb8[8];
        #pragma unroll
        for (int p = 0; p < 4; ++p) {
            const unsigned int hp = hA[dt][p];
            hf8[2 * p]     = bf2f(hp & 0xffffu);
            hf8[2 * p + 1] = bf2f(hp >> 16);
            hb8[2 * p]     = fabsf(hf8[2 * p]);
            hb8[2 * p + 1] = fabsf(hf8[2 * p + 1]);
        }
        u32x4 U[4], V[4];
        #pragma unroll
        for (int k = 0; k < 4; ++k) {
            const float* ap = (k == 0) ? a0 : (k == 1) ? a1 : (k == 2) ? a2 : a3;
            const float4 aL = *(const float4*)(ap + dt * 32 + goff);
            const float4 aH = *(const float4*)(ap + dt * 32 + goff + 4);
            const float a8[8] = {aL.x, aL.y, aL.z, aL.w, aH.x, aH.y, aH.z, aH.w};
            #pragma unroll
            for (int p = 0; p < 4; ++p) {
                U[k][p] = pack2(0.6f * a8[2 * p] * hf8[2 * p],
                                0.6f * a8[2 * p + 1] * hf8[2 * p + 1]);
                V[k][p] = pack2(0.4f * a8[2 * p] * hb8[2 * p],
                                0.4f * a8[2 * p + 1] * hb8[2 * p + 1]);
            }
        }
        #pragma unroll
        for (int jt = 0; jt < 4; ++jt) {
            const u32x4 hB = *(const u32x4*)(const void*)(sh + H_OFF + (jt * 16 + c) * H_S + dt * 32 + goff);
            u32x4 hBa;
            #pragma unroll
            for (int p = 0; p < 4; ++p) hBa[p] = hB[p] & 0x7fff7fffu;
            #pragma unroll
            for (int k = 0; k < 4; ++k) {
                accS[jt][k] = mfma16(U[k], hB,  accS[jt][k]);
                accS[jt][k] = mfma16(V[k], hBa, accS[jt][k]);
            }
        }
    }

    // ---- adj select + in-register softmax (C/D: col=c, row=g*4+reg) ----
    float s_[4][4];
    #pragma unroll
    for (int jt = 0; jt < 4; ++jt) {
        #pragma unroll
        for (int reg = 0; reg < 4; ++reg) {
            const int il = w * 16 + g * 4 + reg;
            const int j  = jt * 16 + c;
            const int a  = (int)sh[ADJ_OFF + il * 64 + j];
            float sv = (a == 1) ? accS[jt][0][reg] : (a == 2) ? accS[jt][1][reg]
                     : (a == 3) ? accS[jt][2][reg] : (a == 4) ? accS[jt][3][reg] : NEGV;
            if (j >= NN) sv = -INFINITY;
            s_[jt][reg] = sv;
        }
    }
    #pragma unroll
    for (int reg = 0; reg < 4; ++reg) {
        float m = fmaxf(fmaxf(s_[0][reg], s_[1][reg]), fmaxf(s_[2][reg], s_[3][reg]));
        m = fmaxf(m, __shfl_xor(m, 1));
        m = fmaxf(m, __shfl_xor(m, 2));
        m = fmaxf(m, __shfl_xor(m, 4));
        m = fmaxf(m, __shfl_xor(m, 8));
        const float p0 = __expf(s_[0][reg] - m);
        const float p1 = __expf(s_[1][reg] - m);
        const float p2 = __expf(s_[2][reg] - m);
        const float p3 = __expf(s_[3][reg] - m);
        float sum = (p0 + p1) + (p2 + p3);
        sum += __shfl_xor(sum, 1);
        sum += __shfl_xor(sum, 2);
        sum += __shfl_xor(sum, 4);
        sum += __shfl_xor(sum, 8);
        const float r  = 1.0f / sum;
        const int  il  = w * 16 + g * 4 + reg;
        sh[AL_OFF + il * AL_S +  0 + c] = (unsigned short)pack2(p0 * r, p0 * r);
        sh[AL_OFF + il * AL_S + 16 + c] = (unsigned short)pack2(p1 * r, p1 * r);
        sh[AL_OFF + il * AL_S + 32 + c] = (unsigned short)pack2(p2 * r, p2 * r);
        sh[AL_OFF + il * AL_S + 48 + c] = (unsigned short)pack2(p3 * r, p3 * r);
    }
    // no barrier: PV reads only THIS wave's alpha rows (within-wave LDS order)

    // ---- PV: out rows of this wave's i-tile, 8 n-tiles ----
    const int il = w * 16 + c;
    const u32x4 pa0 = *(const u32x4*)(const void*)(sh + AL_OFF + il * AL_S + goff);
    const u32x4 pa1 = *(const u32x4*)(const void*)(sh + AL_OFF + il * AL_S + 32 + goff);
    #pragma unroll
    for (int nt = 0; nt < 8; ++nt) {
        const u32x4 v0 = *(const u32x4*)(const void*)(sh + HT_OFF + (nt * 16 + c) * HT_S + goff);
        const u32x4 v1 = *(const u32x4*)(const void*)(sh + HT_OFF + (nt * 16 + c) * HT_S + 32 + goff);
        f32x4 accp = (f32x4){0.f, 0.f, 0.f, 0.f};
        accp = mfma16(pa0, v0, accp);
        accp = mfma16(pa1, v1, accp);
        #pragma unroll
        for (int reg = 0; reg < 4; ++reg) {
            const int ig = w * 16 + g * 4 + reg;
            if (ig < NN)
                out[((size_t)b * NN + ig) * DD + nt * 16 + c] = accp[reg];
        }
    }
}

extern "C" void kernel_launch(void* const* d_in, const int* in_sizes, int n_in,
                              void* d_out, int out_size, void* d_ws, size_t ws_size,
                              hipStream_t stream) {
    const int*   inputs    = (const int*)  d_in[0];
    const int*   adj       = (const int*)  d_in[1];
    // d_in[2] = mask_item (unused by the reference)
    const float* A_attr    = (const float*)d_in[3];
    const float* embedding = (const float*)d_in[4];
    const float* attr_emb  = (const float*)d_in[5];
    const float* a0        = (const float*)d_in[6];
    const float* a1        = (const float*)d_in[7];
    const float* a2        = (const float*)d_in[8];
    const float* a3        = (const float*)d_in[9];

    float* out      = (float*)d_out;                 // [B,N,D] flat
    float* attr_out = out + (size_t)BB * NN * DD;    // [B,D] flat, concatenated

    // single dispatch: 32 attr blocks (full-K, direct store) + 256 GAT blocks
    sg_fused_kernel<<<NATTR + BB, 256, 0, stream>>>(inputs, adj, A_attr, embedding,
                                                    attr_emb, a0, a1, a2, a3,
                                                    out, attr_out);
}

// Round 14
// 20.497 us; speedup vs baseline: 2.6006x; 2.6006x over previous
//
#include <hip/hip_runtime.h>
#include <math.h>

#define BB 256
#define NN 50
#define DD 128
#define MAXA 2000
#define NEGV -9e15f
#define NATTR 256                      // 16 m-groups x 16 k-splits

// u16 strides; 16B-granule strides are ODD (17/9/5) -> bank-quads balanced, NO XOR
#define H_S   136                      // H  [64 i][128 d + pad]
#define HT_S  72                       // HT [128 d][64 i + pad]
#define AL_S  72                       // alpha [64 i][64 j + pad]

#define H_OFF   0
#define HT_OFF  (64 * H_S)             // 8704
#define AL_OFF  (HT_OFF + 128 * HT_S)  // 17920
#define ADJ_OFF (AL_OFF + 64 * AL_S)   // 22528
#define LDS_US  (ADJ_OFF + 64 * 64)    // 26624 u16 = 53248 B

typedef __attribute__((ext_vector_type(8))) short        s8b;
typedef __attribute__((ext_vector_type(4))) float        f32x4;
typedef __attribute__((ext_vector_type(4))) unsigned int u32x4;

// HW packed f32x2 -> bf16x2 (RNE), 1 VALU op (no builtin on gfx950 -> asm)
static __device__ __forceinline__ unsigned int pack2(float lo, float hi) {
    unsigned int r;
    asm("v_cvt_pk_bf16_f32 %0, %1, %2" : "=v"(r) : "v"(lo), "v"(hi));
    return r;
}
static __device__ __forceinline__ float bf2f(unsigned int s) {
    return __uint_as_float(s << 16);
}
static __device__ __forceinline__ f32x4 mfma16(u32x4 a, u32x4 b, f32x4 c) {
    return __builtin_amdgcn_mfma_f32_16x16x32_bf16(
        __builtin_bit_cast(s8b, a), __builtin_bit_cast(s8b, b), c, 0, 0, 0);
}

__global__ __launch_bounds__(256) void sg_fused_kernel(
    const int* __restrict__ inputs,      // [B,N]
    const int* __restrict__ adj,         // [B,N,N]
    const float* __restrict__ A_attr,    // [B,MAXA]
    const float* __restrict__ embedding, // [N_NODE,D]
    const float* __restrict__ attr_emb,  // [MAXA,D]
    const float* __restrict__ a0,
    const float* __restrict__ a1,
    const float* __restrict__ a2,
    const float* __restrict__ a3,
    float* __restrict__ out,             // [B,N,D]
    float* __restrict__ ws)              // [256][16][128] f32 attr partials
{
    __shared__ __align__(16) unsigned short sh[LDS_US];
    const int blk  = blockIdx.x;
    const int tid  = threadIdx.x;
    const int w    = tid >> 6;
    const int lane = tid & 63;
    const int g    = lane >> 4;
    const int c    = lane & 15;
    const int goff = g * 8;

    if (blk < BB) {
        // ================= GAT: one block per batch, wave w = i-tile w =================
        const int b = blk;

        // ---- issue embedding gathers EARLY (latency hides under adj staging) ----
        const int  i_   = lane;
        const bool live = (i_ < NN);
        int node = 0;
        if (live) node = inputs[b * NN + i_];
        float4 gv[8];
        #pragma unroll
        for (int n = 0; n < 8; ++n) {
            gv[n] = make_float4(0.f, 0.f, 0.f, 0.f);
            if (live) gv[n] = *(const float4*)(embedding + (size_t)node * DD + (w * 8 + n) * 4);
        }
        // ---- adj -> LDS (zero-padded to 64x64) ----
        for (int idx = tid; idx < 4096; idx += 256) {
            const int i = idx >> 6, j = idx & 63;
            int a = 0;
            if (i < NN && j < NN) a = adj[(size_t)b * (NN * NN) + i * NN + j];
            sh[ADJ_OFF + idx] = (unsigned short)a;
        }
        // ---- convert (cvt_pk) + store H (row-major) and HT (transposed) ----
        #pragma unroll
        for (int n = 0; n < 8; ++n) {
            const int d4 = w * 8 + n;
            const unsigned int pk01 = pack2(gv[n].x, gv[n].y);
            const unsigned int pk23 = pack2(gv[n].z, gv[n].w);
            *(uint2*)(sh + H_OFF + i_ * H_S + d4 * 4) = make_uint2(pk01, pk23);
            sh[HT_OFF + (d4 * 4 + 0) * HT_S + i_] = (unsigned short)pk01;
            sh[HT_OFF + (d4 * 4 + 1) * HT_S + i_] = (unsigned short)(pk01 >> 16);
            sh[HT_OFF + (d4 * 4 + 2) * HT_S + i_] = (unsigned short)pk23;
            sh[HT_OFF + (d4 * 4 + 3) * HT_S + i_] = (unsigned short)(pk23 >> 16);
        }
        __syncthreads();

        // ---- this wave's A-side row fragments ----
        u32x4 hA[4];
        #pragma unroll
        for (int dt = 0; dt < 4; ++dt)
            hA[dt] = *(const u32x4*)(const void*)(sh + H_OFF + (w * 16 + c) * H_S + dt * 32 + goff);

        // ---- scores, dt-outer: e_k = (H⊙0.6a_k)·H^T + (|H|⊙0.4a_k)·|H|^T ----
        f32x4 accS[4][4];                 // [jt][k]
        #pragma unroll
        for (int jt = 0; jt < 4; ++jt)
            #pragma unroll
            for (int k = 0; k < 4; ++k) accS[jt][k] = (f32x4){0.f, 0.f, 0.f, 0.f};

        #pragma unroll
        for (int dt = 0; dt < 4; ++dt) {
            float hf8[8], hb8[8];
            #pragma unroll
            for (int p = 0; p < 4; ++p) {
                const unsigned int hp = hA[dt][p];
                hf8[2 * p]     = bf2f(hp & 0xffffu);
                hf8[2 * p + 1] = bf2f(hp >> 16);
                hb8[2 * p]     = fabsf(hf8[2 * p]);
                hb8[2 * p + 1] = fabsf(hf8[2 * p + 1]);
            }
            u32x4 U[4], V[4];
            #pragma unroll
            for (int k = 0; k < 4; ++k) {
                const float* ap = (k == 0) ? a0 : (k == 1) ? a1 : (k == 2) ? a2 : a3;
                const float4 aL = *(const float4*)(ap + dt * 32 + goff);
                const float4 aH = *(const float4*)(ap + dt * 32 + goff + 4);
                const float a8[8] = {aL.x, aL.y, aL.z, aL.w, aH.x, aH.y, aH.z, aH.w};
                #pragma unroll
                for (int p = 0; p < 4; ++p) {
                    U[k][p] = pack2(0.6f * a8[2 * p] * hf8[2 * p],
                                    0.6f * a8[2 * p + 1] * hf8[2 * p + 1]);
                    V[k][p] = pack2(0.4f * a8[2 * p] * hb8[2 * p],
                                    0.4f * a8[2 * p + 1] * hb8[2 * p + 1]);
                }
            }
            #pragma unroll
            for (int jt = 0; jt < 4; ++jt) {
                const u32x4 hB = *(const u32x4*)(const void*)(sh + H_OFF + (jt * 16 + c) * H_S + dt * 32 + goff);
                u32x4 hBa;
                #pragma unroll
                for (int p = 0; p < 4; ++p) hBa[p] = hB[p] & 0x7fff7fffu;
                #pragma unroll
                for (int k = 0; k < 4; ++k) {
                    accS[jt][k] = mfma16(U[k], hB,  accS[jt][k]);
                    accS[jt][k] = mfma16(V[k], hBa, accS[jt][k]);
                }
            }
        }

        // ---- adj select + in-register softmax (C/D: col=c, row=g*4+reg) ----
        float s_[4][4];
        #pragma unroll
        for (int jt = 0; jt < 4; ++jt) {
            #pragma unroll
            for (int reg = 0; reg < 4; ++reg) {
                const int il = w * 16 + g * 4 + reg;
                const int j  = jt * 16 + c;
                const int a  = (int)sh[ADJ_OFF + il * 64 + j];
                float sv = (a == 1) ? accS[jt][0][reg] : (a == 2) ? accS[jt][1][reg]
                         : (a == 3) ? accS[jt][2][reg] : (a == 4) ? accS[jt][3][reg] : NEGV;
                if (j >= NN) sv = -INFINITY;
                s_[jt][reg] = sv;
            }
        }
        #pragma unroll
        for (int reg = 0; reg < 4; ++reg) {
            float m = fmaxf(fmaxf(s_[0][reg], s_[1][reg]), fmaxf(s_[2][reg], s_[3][reg]));
            m = fmaxf(m, __shfl_xor(m, 1));
            m = fmaxf(m, __shfl_xor(m, 2));
            m = fmaxf(m, __shfl_xor(m, 4));
            m = fmaxf(m, __shfl_xor(m, 8));
            const float p0 = __expf(s_[0][reg] - m);
            const float p1 = __expf(s_[1][reg] - m);
            const float p2 = __expf(s_[2][reg] - m);
            const float p3 = __expf(s_[3][reg] - m);
            float sum = (p0 + p1) + (p2 + p3);
            sum += __shfl_xor(sum, 1);
            sum += __shfl_xor(sum, 2);
            sum += __shfl_xor(sum, 4);
            sum += __shfl_xor(sum, 8);
            const float r  = 1.0f / sum;
            const int  il  = w * 16 + g * 4 + reg;
            sh[AL_OFF + il * AL_S +  0 + c] = (unsigned short)pack2(p0 * r, p0 * r);
            sh[AL_OFF + il * AL_S + 16 + c] = (unsigned short)pack2(p1 * r, p1 * r);
            sh[AL_OFF + il * AL_S + 32 + c] = (unsigned short)pack2(p2 * r, p2 * r);
            sh[AL_OFF + il * AL_S + 48 + c] = (unsigned short)pack2(p3 * r, p3 * r);
        }
        // no barrier: PV reads only THIS wave's alpha rows (within-wave LDS order)

        // ---- PV: out rows of this wave's i-tile, 8 n-tiles ----
        const int il = w * 16 + c;
        const u32x4 pa0 = *(const u32x4*)(const void*)(sh + AL_OFF + il * AL_S + goff);
        const u32x4 pa1 = *(const u32x4*)(const void*)(sh + AL_OFF + il * AL_S + 32 + goff);
        #pragma unroll
        for (int nt = 0; nt < 8; ++nt) {
            const u32x4 v0 = *(const u32x4*)(const void*)(sh + HT_OFF + (nt * 16 + c) * HT_S + goff);
            const u32x4 v1 = *(const u32x4*)(const void*)(sh + HT_OFF + (nt * 16 + c) * HT_S + 32 + goff);
            f32x4 accp = (f32x4){0.f, 0.f, 0.f, 0.f};
            accp = mfma16(pa0, v0, accp);
            accp = mfma16(pa1, v1, accp);
            #pragma unroll
            for (int reg = 0; reg < 4; ++reg) {
                const int ig = w * 16 + g * 4 + reg;
                if (ig < NN)
                    out[((size_t)b * NN + ig) * DD + nt * 16 + c] = accp[reg];
            }
        }
    } else {
        // ===== attr GEMM: 16-way k-split, ALL 4 chunks' loads issued up-front =====
        const int ablk = blk - BB;
        const int mg = ablk >> 4;
        const int ks = ablk & 15;
        const int m0 = mg * 16;
        const int wd = w * 32;
        const float* Arow = A_attr + (size_t)(m0 + c) * MAXA;

        const int k0 = (ks +  0) * 32;
        const int k1 = (ks + 16) * 32;
        const int k2 = (ks + 32) * 32;
        const int k3 = (ks + 48) * 32;
        const bool has3 = (ks < 15);        // chunk 63 doesn't exist
        const bool gd3  = (ks == 14);       // chunk 62 has partial tail

        // ---- A loads (chunks 0-2 provably in-bounds; 3 guarded) ----
        const float4 aL0 = *(const float4*)(Arow + k0 + goff);
        const float4 aH0 = *(const float4*)(Arow + k0 + goff + 4);
        const float4 aL1 = *(const float4*)(Arow + k1 + goff);
        const float4 aH1 = *(const float4*)(Arow + k1 + goff + 4);
        const float4 aL2 = *(const float4*)(Arow + k2 + goff);
        const float4 aH2 = *(const float4*)(Arow + k2 + goff + 4);
        float4 aL3 = make_float4(0.f, 0.f, 0.f, 0.f);
        float4 aH3 = make_float4(0.f, 0.f, 0.f, 0.f);
        if (has3) {
            if (!gd3 || k3 + goff + 3 < MAXA) aL3 = *(const float4*)(Arow + k3 + goff);
            if (!gd3 || k3 + goff + 7 < MAXA) aH3 = *(const float4*)(Arow + k3 + goff + 4);
        }
        // ---- E loads, all chunks ----
        float ev0[2][8], ev1[2][8], ev2[2][8], ev3[2][8];
        #pragma unroll
        for (int ntl = 0; ntl < 2; ++ntl) {
            const int col = wd + ntl * 16 + c;
            #pragma unroll
            for (int p = 0; p < 8; ++p) {
                ev0[ntl][p] = attr_emb[(size_t)(k0 + goff + p) * DD + col];
                ev1[ntl][p] = attr_emb[(size_t)(k1 + goff + p) * DD + col];
                ev2[ntl][p] = attr_emb[(size_t)(k2 + goff + p) * DD + col];
                const int kr = k3 + goff + p;
                ev3[ntl][p] = (has3 && (!gd3 || kr < MAXA))
                                  ? attr_emb[(size_t)kr * DD + col] : 0.f;
            }
        }
        // ---- pack + MFMA all 4 chunks ----
        f32x4 acc2[2];
        acc2[0] = (f32x4){0.f, 0.f, 0.f, 0.f};
        acc2[1] = (f32x4){0.f, 0.f, 0.f, 0.f};
        #define ATTR_CHUNK(AL, AH, EV)                                              \
        {                                                                           \
            u32x4 af;                                                               \
            af[0] = pack2(AL.x, AL.y); af[1] = pack2(AL.z, AL.w);                   \
            af[2] = pack2(AH.x, AH.y); af[3] = pack2(AH.z, AH.w);                   \
            _Pragma("unroll")                                                       \
            for (int ntl = 0; ntl < 2; ++ntl) {                                     \
                u32x4 bf_;                                                          \
                bf_[0] = pack2(EV[ntl][0], EV[ntl][1]);                             \
                bf_[1] = pack2(EV[ntl][2], EV[ntl][3]);                             \
                bf_[2] = pack2(EV[ntl][4], EV[ntl][5]);                             \
                bf_[3] = pack2(EV[ntl][6], EV[ntl][7]);                             \
                acc2[ntl] = mfma16(af, bf_, acc2[ntl]);                             \
            }                                                                       \
        }
        ATTR_CHUNK(aL0, aH0, ev0)
        ATTR_CHUNK(aL1, aH1, ev1)
        ATTR_CHUNK(aL2, aH2, ev2)
        ATTR_CHUNK(aL3, aH3, ev3)
        #undef ATTR_CHUNK

        // store partial tile (deterministic slot, fully overwritten every call)
        float* pt = ws + (size_t)ablk * (16 * DD);
        #pragma unroll
        for (int ntl = 0; ntl < 2; ++ntl)
            #pragma unroll
            for (int reg = 0; reg < 4; ++reg)
                pt[(g * 4 + reg) * DD + wd + ntl * 16 + c] = acc2[ntl][reg];
    }
}

// sum the 16 k-split partials per output element (float4-vectorized, 32 blocks)
__global__ __launch_bounds__(256) void attr_reduce_kernel(
    const float* __restrict__ ws, float* __restrict__ attr_out)
{
    const int idx = blockIdx.x * 256 + threadIdx.x;   // 0..8191
    const int m  = idx >> 5;             // 0..255
    const int d4 = idx & 31;
    const int mg = m >> 4;
    const int r  = m & 15;
    const float4* base = (const float4*)ws + (size_t)(mg * 16) * 512 + r * 32 + d4;
    float4 v = make_float4(0.f, 0.f, 0.f, 0.f);
    #pragma unroll
    for (int ks = 0; ks < 16; ++ks) {
        const float4 t = base[(size_t)ks * 512];
        v.x += t.x; v.y += t.y; v.z += t.z; v.w += t.w;
    }
    ((float4*)attr_out)[(size_t)m * 32 + d4] = v;
}

extern "C" void kernel_launch(void* const* d_in, const int* in_sizes, int n_in,
                              void* d_out, int out_size, void* d_ws, size_t ws_size,
                              hipStream_t stream) {
    const int*   inputs    = (const int*)  d_in[0];
    const int*   adj       = (const int*)  d_in[1];
    // d_in[2] = mask_item (unused by the reference)
    const float* A_attr    = (const float*)d_in[3];
    const float* embedding = (const float*)d_in[4];
    const float* attr_emb  = (const float*)d_in[5];
    const float* a0        = (const float*)d_in[6];
    const float* a1        = (const float*)d_in[7];
    const float* a2        = (const float*)d_in[8];
    const float* a3        = (const float*)d_in[9];

    float* out      = (float*)d_out;                 // [B,N,D] flat
    float* attr_out = out + (size_t)BB * NN * DD;    // [B,D] flat, concatenated
    float* ws       = (float*)d_ws;                  // 256*2048 f32 = 2 MB

    sg_fused_kernel<<<BB + NATTR, 256, 0, stream>>>(inputs, adj, A_attr, embedding,
                                                    attr_emb, a0, a1, a2, a3,
                                                    out, ws);
    attr_reduce_kernel<<<32, 256, 0, stream>>>(ws, attr_out);
}

// Round 15
// 20.032 us; speedup vs baseline: 2.6609x; 1.0232x over previous
//
#include <hip/hip_runtime.h>
#include <math.h>

#define BB 256
#define NN 50
#define DD 128
#define MAXA 2000
#define NEGV -9e15f
#define NATTR 64                       // 16 m-groups x 4 col-quarters; k-split across waves

// u16 strides; 16B-granule strides are ODD (17/9/5) -> bank-quads balanced, NO XOR
#define H_S   136                      // H  [64 i][128 d + pad]
#define HT_S  72                       // HT [128 d][64 i + pad]
#define AL_S  72                       // alpha [64 i][64 j + pad]

#define H_OFF   0
#define HT_OFF  (64 * H_S)             // 8704
#define AL_OFF  (HT_OFF + 128 * HT_S)  // 17920
#define ADJ_OFF (AL_OFF + 64 * AL_S)   // 22528
#define LDS_US  (ADJ_OFF + 64 * 64)    // 26624 u16 = 53248 B

typedef __attribute__((ext_vector_type(8))) short        s8b;
typedef __attribute__((ext_vector_type(4))) float        f32x4;
typedef __attribute__((ext_vector_type(4))) unsigned int u32x4;

// HW packed f32x2 -> bf16x2 (RNE), 1 VALU op (no builtin on gfx950 -> asm)
static __device__ __forceinline__ unsigned int pack2(float lo, float hi) {
    unsigned int r;
    asm("v_cvt_pk_bf16_f32 %0, %1, %2" : "=v"(r) : "v"(lo), "v"(hi));
    return r;
}
static __device__ __forceinline__ float bf2f(unsigned int s) {
    return __uint_as_float(s << 16);
}
static __device__ __forceinline__ f32x4 mfma16(u32x4 a, u32x4 b, f32x4 c) {
    return __builtin_amdgcn_mfma_f32_16x16x32_bf16(
        __builtin_bit_cast(s8b, a), __builtin_bit_cast(s8b, b), c, 0, 0, 0);
}

__global__ __launch_bounds__(256) void sg_fused_kernel(
    const int* __restrict__ inputs,      // [B,N]
    const int* __restrict__ adj,         // [B,N,N]
    const float* __restrict__ A_attr,    // [B,MAXA]
    const float* __restrict__ embedding, // [N_NODE,D]
    const float* __restrict__ attr_emb,  // [MAXA,D]
    const float* __restrict__ a0,
    const float* __restrict__ a1,
    const float* __restrict__ a2,
    const float* __restrict__ a3,
    float* __restrict__ out,             // [B,N,D]
    float* __restrict__ attr_out)        // [B,D]
{
    __shared__ __align__(16) unsigned short sh[LDS_US];
    const int blk  = blockIdx.x;
    const int tid  = threadIdx.x;
    const int w    = tid >> 6;
    const int lane = tid & 63;
    const int g    = lane >> 4;
    const int c    = lane & 15;
    const int goff = g * 8;

    if (blk < BB) {
        // ================= GAT: one block per batch, wave w = i-tile w =================
        const int b = blk;

        // ---- issue embedding gathers EARLY (latency hides under adj staging) ----
        const int  i_   = lane;
        const bool live = (i_ < NN);
        int node = 0;
        if (live) node = inputs[b * NN + i_];
        float4 gv[8];
        #pragma unroll
        for (int n = 0; n < 8; ++n) {
            gv[n] = make_float4(0.f, 0.f, 0.f, 0.f);
            if (live) gv[n] = *(const float4*)(embedding + (size_t)node * DD + (w * 8 + n) * 4);
        }
        // ---- adj -> LDS (zero-padded to 64x64) ----
        for (int idx = tid; idx < 4096; idx += 256) {
            const int i = idx >> 6, j = idx & 63;
            int a = 0;
            if (i < NN && j < NN) a = adj[(size_t)b * (NN * NN) + i * NN + j];
            sh[ADJ_OFF + idx] = (unsigned short)a;
        }
        // ---- convert (cvt_pk) + store H (row-major) and HT (transposed) ----
        #pragma unroll
        for (int n = 0; n < 8; ++n) {
            const int d4 = w * 8 + n;
            const unsigned int pk01 = pack2(gv[n].x, gv[n].y);
            const unsigned int pk23 = pack2(gv[n].z, gv[n].w);
            *(uint2*)(sh + H_OFF + i_ * H_S + d4 * 4) = make_uint2(pk01, pk23);
            sh[HT_OFF + (d4 * 4 + 0) * HT_S + i_] = (unsigned short)pk01;
            sh[HT_OFF + (d4 * 4 + 1) * HT_S + i_] = (unsigned short)(pk01 >> 16);
            sh[HT_OFF + (d4 * 4 + 2) * HT_S + i_] = (unsigned short)pk23;
            sh[HT_OFF + (d4 * 4 + 3) * HT_S + i_] = (unsigned short)(pk23 >> 16);
        }
        __syncthreads();

        // ---- this wave's A-side row fragments ----
        u32x4 hA[4];
        #pragma unroll
        for (int dt = 0; dt < 4; ++dt)
            hA[dt] = *(const u32x4*)(const void*)(sh + H_OFF + (w * 16 + c) * H_S + dt * 32 + goff);

        // ---- scores, dt-outer: e_k = (H⊙0.6a_k)·H^T + (|H|⊙0.4a_k)·|H|^T ----
        f32x4 accS[4][4];                 // [jt][k]
        #pragma unroll
        for (int jt = 0; jt < 4; ++jt)
            #pragma unroll
            for (int k = 0; k < 4; ++k) accS[jt][k] = (f32x4){0.f, 0.f, 0.f, 0.f};

        #pragma unroll
        for (int dt = 0; dt < 4; ++dt) {
            float hf8[8], hb8[8];
            #pragma unroll
            for (int p = 0; p < 4; ++p) {
                const unsigned int hp = hA[dt][p];
                hf8[2 * p]     = bf2f(hp & 0xffffu);
                hf8[2 * p + 1] = bf2f(hp >> 16);
                hb8[2 * p]     = fabsf(hf8[2 * p]);
                hb8[2 * p + 1] = fabsf(hf8[2 * p + 1]);
            }
            u32x4 U[4], V[4];
            #pragma unroll
            for (int k = 0; k < 4; ++k) {
                const float* ap = (k == 0) ? a0 : (k == 1) ? a1 : (k == 2) ? a2 : a3;
                const float4 aL = *(const float4*)(ap + dt * 32 + goff);
                const float4 aH = *(const float4*)(ap + dt * 32 + goff + 4);
                const float a8[8] = {aL.x, aL.y, aL.z, aL.w, aH.x, aH.y, aH.z, aH.w};
                #pragma unroll
                for (int p = 0; p < 4; ++p) {
                    U[k][p] = pack2(0.6f * a8[2 * p] * hf8[2 * p],
                                    0.6f * a8[2 * p + 1] * hf8[2 * p + 1]);
                    V[k][p] = pack2(0.4f * a8[2 * p] * hb8[2 * p],
                                    0.4f * a8[2 * p + 1] * hb8[2 * p + 1]);
                }
            }
            #pragma unroll
            for (int jt = 0; jt < 4; ++jt) {
                const u32x4 hB = *(const u32x4*)(const void*)(sh + H_OFF + (jt * 16 + c) * H_S + dt * 32 + goff);
                u32x4 hBa;
                #pragma unroll
                for (int p = 0; p < 4; ++p) hBa[p] = hB[p] & 0x7fff7fffu;
                #pragma unroll
                for (int k = 0; k < 4; ++k) {
                    accS[jt][k] = mfma16(U[k], hB,  accS[jt][k]);
                    accS[jt][k] = mfma16(V[k], hBa, accS[jt][k]);
                }
            }
        }

        // ---- adj select + in-register softmax (C/D: col=c, row=g*4+reg) ----
        float s_[4][4];
        #pragma unroll
        for (int jt = 0; jt < 4; ++jt) {
            #pragma unroll
            for (int reg = 0; reg < 4; ++reg) {
                const int il = w * 16 + g * 4 + reg;
                const int j  = jt * 16 + c;
                const int a  = (int)sh[ADJ_OFF + il * 64 + j];
                float sv = (a == 1) ? accS[jt][0][reg] : (a == 2) ? accS[jt][1][reg]
                         : (a == 3) ? accS[jt][2][reg] : (a == 4) ? accS[jt][3][reg] : NEGV;
                if (j >= NN) sv = -INFINITY;
                s_[jt][reg] = sv;
            }
        }
        #pragma unroll
        for (int reg = 0; reg < 4; ++reg) {
            float m = fmaxf(fmaxf(s_[0][reg], s_[1][reg]), fmaxf(s_[2][reg], s_[3][reg]));
            m = fmaxf(m, __shfl_xor(m, 1));
            m = fmaxf(m, __shfl_xor(m, 2));
            m = fmaxf(m, __shfl_xor(m, 4));
            m = fmaxf(m, __shfl_xor(m, 8));
            const float p0 = __expf(s_[0][reg] - m);
            const float p1 = __expf(s_[1][reg] - m);
            const float p2 = __expf(s_[2][reg] - m);
            const float p3 = __expf(s_[3][reg] - m);
            float sum = (p0 + p1) + (p2 + p3);
            sum += __shfl_xor(sum, 1);
            sum += __shfl_xor(sum, 2);
            sum += __shfl_xor(sum, 4);
            sum += __shfl_xor(sum, 8);
            const float r  = 1.0f / sum;
            const int  il  = w * 16 + g * 4 + reg;
            sh[AL_OFF + il * AL_S +  0 + c] = (unsigned short)pack2(p0 * r, p0 * r);
            sh[AL_OFF + il * AL_S + 16 + c] = (unsigned short)pack2(p1 * r, p1 * r);
            sh[AL_OFF + il * AL_S + 32 + c] = (unsigned short)pack2(p2 * r, p2 * r);
            sh[AL_OFF + il * AL_S + 48 + c] = (unsigned short)pack2(p3 * r, p3 * r);
        }
        // no barrier: PV reads only THIS wave's alpha rows (within-wave LDS order)

        // ---- PV: out rows of this wave's i-tile, 8 n-tiles ----
        const int il = w * 16 + c;
        const u32x4 pa0 = *(const u32x4*)(const void*)(sh + AL_OFF + il * AL_S + goff);
        const u32x4 pa1 = *(const u32x4*)(const void*)(sh + AL_OFF + il * AL_S + 32 + goff);
        #pragma unroll
        for (int nt = 0; nt < 8; ++nt) {
            const u32x4 v0 = *(const u32x4*)(const void*)(sh + HT_OFF + (nt * 16 + c) * HT_S + goff);
            const u32x4 v1 = *(const u32x4*)(const void*)(sh + HT_OFF + (nt * 16 + c) * HT_S + 32 + goff);
            f32x4 accp = (f32x4){0.f, 0.f, 0.f, 0.f};
            accp = mfma16(pa0, v0, accp);
            accp = mfma16(pa1, v1, accp);
            #pragma unroll
            for (int reg = 0; reg < 4; ++reg) {
                const int ig = w * 16 + g * 4 + reg;
                if (ig < NN)
                    out[((size_t)b * NN + ig) * DD + nt * 16 + c] = accp[reg];
            }
        }
    } else {
        // ===== attr GEMM: in-block 4-way k-split (wave=ks), 4 groups of 4 batched chunks,
        //       LDS reduce, direct store — ZERO ws, ZERO extra dispatch =====
        const int ablk = blk - BB;           // 0..63
        const int mg   = ablk >> 2;          // m-group (16 rows)
        const int cq   = ablk & 3;           // col quarter (32 cols)
        const int m0   = mg * 16;
        const int wd   = cq * 32;
        const int ks   = w;                  // wave = k-split 0..3; chunks ks+4t, t=0..15
        const float* Arow = A_attr + (size_t)(m0 + c) * MAXA;

        f32x4 acc2[2];
        acc2[0] = (f32x4){0.f, 0.f, 0.f, 0.f};
        acc2[1] = (f32x4){0.f, 0.f, 0.f, 0.f};

        #pragma unroll
        for (int u = 0; u < 4; ++u) {        // 4 groups
            float4 aLs[4], aHs[4];
            float  evs[4][2][8];
            // ---- batched loads for the 4 chunks of this group ----
            #pragma unroll
            for (int v = 0; v < 4; ++v) {
                const int  s    = ks + 4 * (4 * u + v);
                const int  k0   = s * 32;
                const bool skip = (s == 63);                 // chunk 63 doesn't exist
                const bool tail = (s == 62);                 // lanes g>=2 fully OOB
                if (!skip && (!tail || g < 2)) {
                    aLs[v] = *(const float4*)(Arow + k0 + goff);
                    aHs[v] = *(const float4*)(Arow + k0 + goff + 4);
                    #pragma unroll
                    for (int ntl = 0; ntl < 2; ++ntl) {
                        const int col = wd + ntl * 16 + c;
                        #pragma unroll
                        for (int p = 0; p < 8; ++p)
                            evs[v][ntl][p] = attr_emb[(size_t)(k0 + goff + p) * DD + col];
                    }
                } else {
                    aLs[v] = make_float4(0.f, 0.f, 0.f, 0.f);
                    aHs[v] = make_float4(0.f, 0.f, 0.f, 0.f);
                    #pragma unroll
                    for (int ntl = 0; ntl < 2; ++ntl)
                        #pragma unroll
                        for (int p = 0; p < 8; ++p) evs[v][ntl][p] = 0.f;
                }
            }
            // ---- pack + MFMA the group ----
            #pragma unroll
            for (int v = 0; v < 4; ++v) {
                u32x4 af;
                af[0] = pack2(aLs[v].x, aLs[v].y); af[1] = pack2(aLs[v].z, aLs[v].w);
                af[2] = pack2(aHs[v].x, aHs[v].y); af[3] = pack2(aHs[v].z, aHs[v].w);
                #pragma unroll
                for (int ntl = 0; ntl < 2; ++ntl) {
                    u32x4 bf_;
                    bf_[0] = pack2(evs[v][ntl][0], evs[v][ntl][1]);
                    bf_[1] = pack2(evs[v][ntl][2], evs[v][ntl][3]);
                    bf_[2] = pack2(evs[v][ntl][4], evs[v][ntl][5]);
                    bf_[3] = pack2(evs[v][ntl][6], evs[v][ntl][7]);
                    acc2[ntl] = mfma16(af, bf_, acc2[ntl]);
                }
            }
        }

        // ---- in-block reduce across the 4 waves: partial [4][16][32] f32 = 8 KB ----
        float* pf = (float*)sh;
        #pragma unroll
        for (int ntl = 0; ntl < 2; ++ntl)
            #pragma unroll
            for (int reg = 0; reg < 4; ++reg)
                pf[((ks * 16) + g * 4 + reg) * 32 + ntl * 16 + c] = acc2[ntl][reg];
        __syncthreads();
        #pragma unroll
        for (int t = 0; t < 2; ++t) {
            const int idx = tid * 2 + t;         // 0..511
            const int row = idx >> 5;            // 0..15
            const int col = idx & 31;
            const float v = pf[(0 * 16 + row) * 32 + col] + pf[(1 * 16 + row) * 32 + col]
                          + pf[(2 * 16 + row) * 32 + col] + pf[(3 * 16 + row) * 32 + col];
            attr_out[(size_t)(m0 + row) * DD + wd + col] = v;
        }
    }
}

extern "C" void kernel_launch(void* const* d_in, const int* in_sizes, int n_in,
                              void* d_out, int out_size, void* d_ws, size_t ws_size,
                              hipStream_t stream) {
    const int*   inputs    = (const int*)  d_in[0];
    const int*   adj       = (const int*)  d_in[1];
    // d_in[2] = mask_item (unused by the reference)
    const float* A_attr    = (const float*)d_in[3];
    const float* embedding = (const float*)d_in[4];
    const float* attr_emb  = (const float*)d_in[5];
    const float* a0        = (const float*)d_in[6];
    const float* a1        = (const float*)d_in[7];
    const float* a2        = (const float*)d_in[8];
    const float* a3        = (const float*)d_in[9];

    float* out      = (float*)d_out;                 // [B,N,D] flat
    float* attr_out = out + (size_t)BB * NN * DD;    // [B,D] flat, concatenated

    // SINGLE dispatch: 256 GAT blocks + 64 self-contained attr blocks
    sg_fused_kernel<<<BB + NATTR, 256, 0, stream>>>(inputs, adj, A_attr, embedding,
                                                    attr_emb, a0, a1, a2, a3,
                                                    out, attr_out);
}